// Round 14
// baseline (435.803 us; speedup 1.0000x reference)
//
#include <hip/hip_runtime.h>
#include <math.h>

#define B 8
#define D 512
#define N 1600
#define NP 1664      // padded N (13 * 128) -- physical row count of split arrays
#define NRES 40

static constexpr float EPS_K   = 1e-6f;
static constexpr float INV_T   = 10.0f;  // 1/T
static constexpr float SCALE_K = 10.0f;
static constexpr float BAND    = 0.99f;  // candidate band (rel. to max K); c-window 1.0e-3
static constexpr float L2E10   = 14.4269504089f; // 10*log2(e)

using f32x4 = __attribute__((ext_vector_type(4))) float;
using h8    = __attribute__((ext_vector_type(8))) _Float16;
using u16x4 = __attribute__((ext_vector_type(4))) unsigned short;

// ---------------- helpers ----------------
__device__ __forceinline__ void gload16(const void* g, void* l) {
    __builtin_amdgcn_global_load_lds(
        (const __attribute__((address_space(1))) void*)g,
        (__attribute__((address_space(3))) void*)l, 16, 0, 0);
}

// ---------------- Kernel A: fp32 -> fp16 transposed + fp32 transposed + norm partials ----------------
__global__ __launch_bounds__(256)
void split_transpose_kernel(const float* __restrict__ f1, const float* __restrict__ f2,
                            short* __restrict__ Xh, short* __restrict__ Yh,
                            float* __restrict__ Xf, float* __restrict__ Yf,
                            float* __restrict__ partial) {
    int bx = blockIdx.x;           // n-tile of 64 (0..25, covers NP)
    int by = blockIdx.y;           // d-tile of 64 (0..7)
    int bz = blockIdx.z;
    int b = bz & 7, which = bz >> 3;
    const float* src = which ? f2 : f1;
    short* oh = which ? Yh : Xh;
    float* of = which ? Yf : Xf;

    __shared__ float Ts[64][65];
    __shared__ float red[64][17];
    int t = threadIdx.x;
    int n0 = bx * 64, d0 = by * 64;
    bool valid = (n0 < N);         // bx==25 is the zero-pad tile
    int c4 = (t & 15) * 4, g16 = t >> 4;

    #pragma unroll
    for (int p = 0; p < 4; ++p) {
        int dl = g16 + p * 16;
        float4 v = make_float4(0.f, 0.f, 0.f, 0.f);
        if (valid) v = *(const float4*)&src[((size_t)b * D + d0 + dl) * N + n0 + c4];
        Ts[dl][c4 + 0] = v.x; Ts[dl][c4 + 1] = v.y;
        Ts[dl][c4 + 2] = v.z; Ts[dl][c4 + 3] = v.w;
    }
    __syncthreads();
    #pragma unroll
    for (int p = 0; p < 4; ++p) {
        int nl = g16 + p * 16;
        float vv[4];
        unsigned int hw[2];
        float ssp = 0.f;
        #pragma unroll
        for (int q = 0; q < 2; ++q) {
            unsigned int wv = 0;
            #pragma unroll
            for (int i = 0; i < 2; ++i) {
                float v = Ts[c4 + q * 2 + i][nl];
                vv[q * 2 + i] = v;
                ssp = fmaf(v, v, ssp);
                _Float16 h = (_Float16)v;            // round-to-nearest-even
                unsigned short hb = __builtin_bit_cast(unsigned short, h);
                wv |= ((unsigned int)hb) << (16 * i);
            }
            hw[q] = wv;
        }
        red[nl][c4 >> 2] = ssp;
        size_t o = ((size_t)b * NP + n0 + nl) * D + d0 + c4;
        *(uint2*)&oh[o] = make_uint2(hw[0], hw[1]);
        *(float4*)&of[o] = make_float4(vv[0], vv[1], vv[2], vv[3]);
    }
    __syncthreads();
    if (t < 64) {
        float s = 0.f;
        #pragma unroll
        for (int g = 0; g < 16; ++g) s += red[t][g];
        partial[(((size_t)which * 8 + b) * 8 + by) * NP + n0 + t] = s;
    }
}

// ---------------- Kernel A2: reduce norm partials ----------------
__global__ __launch_bounds__(256)
void norms_reduce_kernel(const float* __restrict__ partial,
                         float* __restrict__ norm1, float* __restrict__ norm2) {
    int id = blockIdx.x * 256 + threadIdx.x;   // over 2*B*N
    if (id >= 2 * B * N) return;
    int which = id / (B * N);
    int r = id % (B * N);
    int b = r / N, n = r % N;
    float s = 0.f;
    #pragma unroll
    for (int dt = 0; dt < 8; ++dt)
        s += partial[(((size_t)which * 8 + b) * 8 + dt) * NP + n];
    (which ? norm2 : norm1)[b * N + n] = sqrtf(s);
}

// ---------------- Kernel B (fallback path): column norms ----------------
__global__ __launch_bounds__(256)
void norms_kernel(const float* __restrict__ fs1, const float* __restrict__ fs2,
                  float* __restrict__ norm1, float* __restrict__ norm2) {
    int bid   = blockIdx.x;
    int ntile = bid % 25;
    int b     = (bid / 25) % B;
    int which = bid / (25 * B);
    const float* src = which ? fs2 : fs1;
    float*       dst = which ? norm2 : norm1;

    int t = threadIdx.x, nl = t & 63, doff = t >> 6;
    int n = ntile * 64 + nl;
    const float* base = src + (size_t)b * D * N + n;
    float acc = 0.f;
    for (int d = doff; d < D; d += 4) {
        float v = base[(size_t)d * N];
        acc = fmaf(v, v, acc);
    }
    __shared__ float red[4][64];
    red[doff][nl] = acc;
    __syncthreads();
    if (t < 64) {
        float s = red[0][t] + red[1][t] + red[2][t] + red[3][t];
        dst[b * N + ntile * 64 + t] = sqrtf(s);
    }
}

// ---------------- Kernel C: fp16 MFMA GEMM, 128x128, single-buffer 16KB, 8 blocks/CU ----------------
__device__ __forceinline__ h8 ldfragh(const short* tile, int row, int l) {
    int s = ((l >> 4) ^ (row >> 1)) & 3;   // bank-spread XOR swizzle
    return *(const h8*)(tile + row * 32 + s * 8);
}

template<bool USE_KH>
__global__ __launch_bounds__(256, 8)
void gemm_fp16_kernel(const short* __restrict__ Yh, const short* __restrict__ Xh,
                      const float* __restrict__ norm1, const float* __restrict__ norm2,
                      unsigned int* __restrict__ mx, float* __restrict__ out,
                      unsigned short* __restrict__ Kh) {
    // single buffer [A 8KB | B 8KB] = 16KB; 60 VGPR + 64 AGPR = 124 <= 2048/8 -> 8 blocks/CU (32 waves)
    __shared__ short lds[8192];

    int lin = blockIdx.x;          // 1352 = 8 XCD * 169
    int b    = lin & 7;            // one batch per XCD (T1)
    int rem  = lin >> 3;           // 0..168
    int mblk = rem % 13;           // m fastest -> X-panel L2 reuse
    int nblk = rem / 13;           // 0..12
    int m0 = mblk * 128, n0 = nblk * 128;

    int t = threadIdx.x, l = t & 63, w = t >> 6;
    int mwoff = (w & 1) * 64;      // wave tile 64x64
    int nwoff = (w >> 1) * 64;
    size_t bNP = (size_t)b * NP;
    int l15 = l & 15;

    // --- staging: 16 units of 1KB (A rowgroups 0-7, B rowgroups 0-7); 4 gload16/thread ---
    const short* gp[4];
    int lo[4];
    #pragma unroll
    for (int j = 0; j < 4; ++j) {
        int q = w * 4 + j;
        int tile = q >> 3, rg = q & 7;
        int row  = rg * 16 + (l >> 2);
        int slotg = (l & 3) ^ ((row >> 1) & 3);   // pre-swizzled global source
        const short* base = tile ? Xh : Yh;
        int rows0 = tile ? n0 : m0;
        gp[j] = base + (bNP + rows0 + row) * (size_t)D + slotg * 8;
        lo[j] = tile * 4096 + rg * 512;           // wave-uniform LDS base (shorts)
    }

    f32x4 acc[4][4];
    #pragma unroll
    for (int i = 0; i < 4; i++)
        #pragma unroll
        for (int j = 0; j < 4; j++) acc[i][j] = (f32x4)0.f;

    const short* Ah = &lds[0];
    const short* Bh = &lds[4096];

    for (int tt = 0; tt < 16; ++tt) {
        #pragma unroll
        for (int j = 0; j < 4; ++j) {                      // stage K-tile tt
            gload16(gp[j], &lds[lo[j]]);
            gp[j] += 32;
        }
        asm volatile("s_waitcnt vmcnt(0)" ::: "memory");
        __builtin_amdgcn_s_barrier();                      // staged data visible
        asm volatile("" ::: "memory");

        h8 bh[4];
        #pragma unroll
        for (int nj = 0; nj < 4; ++nj)
            bh[nj] = ldfragh(Bh, nwoff + nj * 16 + l15, l);
        __builtin_amdgcn_s_setprio(1);
        #pragma unroll
        for (int mi = 0; mi < 4; ++mi) {
            h8 ah = ldfragh(Ah, mwoff + mi * 16 + l15, l);
            #pragma unroll
            for (int nj = 0; nj < 4; ++nj)
                acc[mi][nj] = __builtin_amdgcn_mfma_f32_16x16x32_f16(ah, bh[nj], acc[mi][nj], 0, 0, 0);
        }
        __builtin_amdgcn_s_setprio(0);
        asm volatile("s_waitcnt lgkmcnt(0)" ::: "memory");  // LDS reads retired before overwrite
        __builtin_amdgcn_s_barrier();
    }

    // epilogue: c = acc*rn1*rn2; K = exp2((c-1)*10*log2e); store K (fp16 to Kh or fp32 to out); per-n max
    int hi4 = l >> 4;
    float rn1v[4];
    int   ng[4];
    #pragma unroll
    for (int nj = 0; nj < 4; ++nj) {
        ng[nj]  = n0 + nwoff + nj * 16 + l15;
        float n1 = (ng[nj] < N) ? norm1[b * N + ng[nj]] : 1.f;
        rn1v[nj] = __builtin_amdgcn_rcpf(n1);
    }
    float pmax[4] = {0.f, 0.f, 0.f, 0.f};
    size_t obase = (size_t)b * N * N;

    #pragma unroll
    for (int mi = 0; mi < 4; ++mi) {
        #pragma unroll
        for (int r = 0; r < 4; ++r) {
            int mg = m0 + mwoff + mi * 16 + hi4 * 4 + r;
            bool mok = (mg < N);
            float rn2 = mok ? __builtin_amdgcn_rcpf(norm2[b * N + mg]) : 1.f;
            #pragma unroll
            for (int nj = 0; nj < 4; ++nj) {
                float c = acc[mi][nj][r] * rn2 * rn1v[nj];
                float k = exp2f((c - 1.f) * L2E10);
                if (!mok) k = 0.f;
                if constexpr (USE_KH) {
                    _Float16 h = (_Float16)k;                 // stored value
                    float kr = (float)h;
                    pmax[nj] = fmaxf(pmax[nj], kr);           // max over STORED values
                    if (mok && ng[nj] < N)
                        Kh[obase + (size_t)mg * N + ng[nj]] = __builtin_bit_cast(unsigned short, h);
                } else {
                    pmax[nj] = fmaxf(pmax[nj], k);
                    if (mok && ng[nj] < N)
                        out[obase + (size_t)mg * N + ng[nj]] = k;
                }
            }
        }
    }
    #pragma unroll
    for (int nj = 0; nj < 4; ++nj) {
        float v = pmax[nj];
        v = fmaxf(v, __shfl_xor(v, 16, 64));
        v = fmaxf(v, __shfl_xor(v, 32, 64));
        if (hi4 == 0 && ng[nj] < N)
            atomicMax(&mx[b * N + ng[nj]], __float_as_uint(v));
    }
}

// ---------------- fp32 fallback GEMM (used if ws too small) ----------------
#define BK 16
#define BT 128
__global__ __launch_bounds__(256)
void gemm_exp_kernel(const float* __restrict__ fs1, const float* __restrict__ fs2,
                     const float* __restrict__ norm1, const float* __restrict__ norm2,
                     unsigned int* __restrict__ mx, float* __restrict__ out) {
    int m0 = blockIdx.x * BT, n0 = blockIdx.y * BT, b = blockIdx.z;
    int t = threadIdx.x, tx = t & 15, ty = t >> 4;
    __shared__ float Xs[BK][BT];
    __shared__ float Ys[BK][BT];
    __shared__ float red[BT][17];
    const float* Xb = fs1 + (size_t)b * D * N;
    const float* Yb = fs2 + (size_t)b * D * N;
    float acc[8][8];
    #pragma unroll
    for (int i = 0; i < 8; i++)
        #pragma unroll
        for (int j = 0; j < 8; j++) acc[i][j] = 0.f;
    int r0 = t >> 5, c4 = (t & 31) * 4;
    bool xok = (n0 + c4) < N, yok = (m0 + c4) < N;
    for (int kk = 0; kk < D; kk += BK) {
        #pragma unroll
        for (int rr = 0; rr < 2; rr++) {
            int r = r0 + rr * 8, d = kk + r;
            float4 xv = make_float4(0, 0, 0, 0), yv = make_float4(0, 0, 0, 0);
            if (xok) xv = *(const float4*)&Xb[(size_t)d * N + n0 + c4];
            if (yok) yv = *(const float4*)&Yb[(size_t)d * N + m0 + c4];
            *(float4*)&Xs[r][c4] = xv;
            *(float4*)&Ys[r][c4] = yv;
        }
        __syncthreads();
        #pragma unroll
        for (int d = 0; d < BK; d++) {
            float4 a0 = *(const float4*)&Xs[d][ty * 4];
            float4 a1 = *(const float4*)&Xs[d][64 + ty * 4];
            float4 b0 = *(const float4*)&Ys[d][tx * 4];
            float4 b1 = *(const float4*)&Ys[d][64 + tx * 4];
            float av[8] = {a0.x, a0.y, a0.z, a0.w, a1.x, a1.y, a1.z, a1.w};
            float bv[8] = {b0.x, b0.y, b0.z, b0.w, b1.x, b1.y, b1.z, b1.w};
            #pragma unroll
            for (int i = 0; i < 8; i++)
                #pragma unroll
                for (int j = 0; j < 8; j++)
                    acc[i][j] = fmaf(av[i], bv[j], acc[i][j]);
        }
        __syncthreads();
    }
    int ng[8], mg[8];
    float n1v[8], n2v[8];
    #pragma unroll
    for (int q = 0; q < 8; q++) {
        ng[q] = n0 + ((q < 4) ? (ty * 4 + q) : (64 + ty * 4 + q - 4));
        mg[q] = m0 + ((q < 4) ? (tx * 4 + q) : (64 + tx * 4 + q - 4));
        n1v[q] = (ng[q] < N) ? norm1[b * N + ng[q]] : 1.f;
        n2v[q] = (mg[q] < N) ? norm2[b * N + mg[q]] : 1.f;
    }
    float pmax[8];
    #pragma unroll
    for (int i = 0; i < 8; i++) pmax[i] = 0.f;
    size_t obase = (size_t)b * N * N;
    #pragma unroll
    for (int j = 0; j < 8; j++) {
        float kcol[8];
        #pragma unroll
        for (int i = 0; i < 8; i++) {
            float c = acc[i][j] / (n1v[i] * n2v[j] + EPS_K);
            float k = expf((c - 1.f) * INV_T);
            if (mg[j] >= N) k = 0.f;
            kcol[i] = k;
            pmax[i] = fmaxf(pmax[i], k);
        }
        if (mg[j] < N) {
            size_t rowb = obase + (size_t)mg[j] * N;
            float4 v0 = {kcol[0], kcol[1], kcol[2], kcol[3]};
            *(float4*)&out[rowb + ng[0]] = v0;
            if (ng[4] < N) {
                float4 v1 = {kcol[4], kcol[5], kcol[6], kcol[7]};
                *(float4*)&out[rowb + ng[4]] = v1;
            }
        }
    }
    #pragma unroll
    for (int q = 0; q < 8; q++) {
        int nloc = (q < 4) ? (ty * 4 + q) : (64 + ty * 4 + q - 4);
        red[nloc][tx] = pmax[q];
    }
    __syncthreads();
    if (t < BT) {
        float mval = red[t][0];
        #pragma unroll
        for (int x = 1; x < 16; x++) mval = fmaxf(mval, red[t][x]);
        int n = n0 + t;
        if (n < N) atomicMax(&mx[b * N + n], __float_as_uint(mval));
    }
}

// ---------------- Kernel D (fp16-K): read Kh, write gm_cls, band-candidate list ----------------
__global__ __launch_bounds__(256)
void fix_argmax_f16_kernel(const unsigned short* __restrict__ Kh, float* __restrict__ out,
                           const unsigned int* __restrict__ mx, int* __restrict__ bestm,
                           unsigned int* __restrict__ candCount, int* __restrict__ candM) {
    int nt = blockIdx.x;      // 0..6 (n chunks of 256)
    int mq = blockIdx.y;      // 0..31 (m chunks of 50)
    int b  = blockIdx.z;
    int t  = threadIdx.x;
    int n0 = nt * 256 + (t & 63) * 4;
    int moff = t >> 6;
    if (n0 >= N) return;      // N%4==0 -> full 4-col group valid or fully out

    float4 mxv = *(const float4*)&((const float*)mx)[b * N + n0];
    float4 th  = make_float4(mxv.x * BAND, mxv.y * BAND, mxv.z * BAND, mxv.w * BAND);
    size_t base = (size_t)b * N * N + n0;
    int mend = mq * 50 + 50;
    for (int m = mq * 50 + moff; m < mend; m += 4) {
        size_t idx = base + (size_t)m * N;
        u16x4 kv = *(const u16x4*)&Kh[idx];
        float k0 = (float)__builtin_bit_cast(_Float16, (unsigned short)kv[0]);
        float k1 = (float)__builtin_bit_cast(_Float16, (unsigned short)kv[1]);
        float k2 = (float)__builtin_bit_cast(_Float16, (unsigned short)kv[2]);
        float k3 = (float)__builtin_bit_cast(_Float16, (unsigned short)kv[3]);
        float4 o;
        o.x = (k0 - mxv.x) * SCALE_K;
        o.y = (k1 - mxv.y) * SCALE_K;
        o.z = (k2 - mxv.z) * SCALE_K;
        o.w = (k3 - mxv.w) * SCALE_K;
        *(float4*)&out[idx] = o;
        #pragma unroll
        for (int j = 0; j < 4; ++j) {
            float vv = (j == 0) ? k0 : (j == 1) ? k1 : (j == 2) ? k2 : k3;
            float tt = (j == 0) ? th.x : (j == 1) ? th.y : (j == 2) ? th.z : th.w;
            if (vv >= tt) {
                int pix = b * N + n0 + j;
                unsigned int slot = atomicAdd(&candCount[pix], 1u);  // scattered, ~1/pixel
                if (slot < 15) candM[pix * 16 + slot] = m;
                atomicMin(&bestm[pix], m);
            }
        }
    }
}

// ---------------- Kernel D (fp32-K in-place, mid fallback) ----------------
__global__ __launch_bounds__(256)
void fix_argmax_kernel(float* __restrict__ out, const unsigned int* __restrict__ mx,
                       int* __restrict__ bestm, unsigned int* __restrict__ candCount,
                       int* __restrict__ candM) {
    int nt = blockIdx.x;
    int mq = blockIdx.y;
    int b  = blockIdx.z;
    int t  = threadIdx.x;
    int n0 = nt * 256 + (t & 63) * 4;
    int moff = t >> 6;
    if (n0 >= N) return;

    float4 mxv = *(const float4*)&((const float*)mx)[b * N + n0];
    float4 th  = make_float4(mxv.x * BAND, mxv.y * BAND, mxv.z * BAND, mxv.w * BAND);
    size_t base = (size_t)b * N * N + n0;
    int mend = mq * 50 + 50;
    for (int m = mq * 50 + moff; m < mend; m += 4) {
        size_t idx = base + (size_t)m * N;
        float4 v = *(float4*)&out[idx];
        float4 o;
        o.x = (v.x - mxv.x) * SCALE_K;
        o.y = (v.y - mxv.y) * SCALE_K;
        o.z = (v.z - mxv.z) * SCALE_K;
        o.w = (v.w - mxv.w) * SCALE_K;
        *(float4*)&out[idx] = o;
        #pragma unroll
        for (int j = 0; j < 4; ++j) {
            float vv = (j == 0) ? v.x : (j == 1) ? v.y : (j == 2) ? v.z : v.w;
            float tt = (j == 0) ? th.x : (j == 1) ? th.y : (j == 2) ? th.z : th.w;
            if (vv >= tt) {
                int pix = b * N + n0 + j;
                unsigned int slot = atomicAdd(&candCount[pix], 1u);
                if (slot < 15) candM[pix * 16 + slot] = m;
                atomicMin(&bestm[pix], m);
            }
        }
    }
}

// ---------------- Kernel D2: exact refinement via candidate list (coalesced fp32T reads) ----------------
__global__ __launch_bounds__(256)
void refine_kernel(const float* __restrict__ Xf, const float* __restrict__ Yf,
                   const float* __restrict__ norm1, const float* __restrict__ norm2,
                   const unsigned int* __restrict__ candCount, const int* __restrict__ candM,
                   int* __restrict__ bestm) {
    int nwaves = (gridDim.x * 256) >> 6;
    int wv = (blockIdx.x * 256 + threadIdx.x) >> 6;
    int l  = threadIdx.x & 63;
    for (int pix = wv; pix < B * N; pix += nwaves) {
        unsigned int cnt = candCount[pix];
        if (cnt < 2) continue;                        // unique band member == exact argmax
        int b = pix / N, n = pix % N;
        const float* p1 = Xf + ((size_t)b * NP + n) * D;
        float n1 = norm1[pix];
        float bestc = -2.f;
        int   bi = N;
        int ncand = (cnt <= 15) ? (int)cnt : N;       // overflow (>15): exact scan of all m
        for (int e = 0; e < ncand; ++e) {
            int m = (cnt <= 15) ? candM[pix * 16 + e] : e;
            const float* p2 = Yf + ((size_t)b * NP + m) * D;
            float acc = 0.f;
            #pragma unroll
            for (int q = 0; q < 2; ++q) {             // lane l: d = l*8 .. l*8+7 (coalesced)
                float4 a = *(const float4*)&p1[l * 8 + q * 4];
                float4 c = *(const float4*)&p2[l * 8 + q * 4];
                acc = fmaf(a.x, c.x, acc);
                acc = fmaf(a.y, c.y, acc);
                acc = fmaf(a.z, c.z, acc);
                acc = fmaf(a.w, c.w, acc);
            }
            #pragma unroll
            for (int off = 1; off < 64; off <<= 1)
                acc += __shfl_xor(acc, off, 64);
            float cc = acc / (n1 * norm2[b * N + m] + EPS_K);
            if (cc > bestc || (cc == bestc && m < bi)) { bestc = cc; bi = m; }  // order-independent
        }
        if (l == 0) bestm[pix] = bi;                  // one wave owns this pixel
    }
}

// ---------------- Kernel D2-fb: fallback refinement (strided originals) ----------------
__global__ __launch_bounds__(256)
void refine_fb_kernel(const float* __restrict__ fs1, const float* __restrict__ fs2,
                      const float* __restrict__ norm1, const float* __restrict__ norm2,
                      const unsigned int* __restrict__ mx, const unsigned int* __restrict__ candCount,
                      int* __restrict__ bestm, const float* __restrict__ out) {
    int nwaves = (gridDim.x * 256) >> 6;
    int wv = (blockIdx.x * 256 + threadIdx.x) >> 6;
    int l  = threadIdx.x & 63;
    for (int pix = wv; pix < B * N; pix += nwaves) {
        if (candCount[pix] < 2) continue;
        int b = pix / N, n = pix % N;
        float mxv = __uint_as_float(mx[pix]);
        float gth = -(1.f - BAND) * SCALE_K * mxv;
        const float* col = out + (size_t)b * N * N + n;
        const float* p1  = fs1 + (size_t)b * D * N + n;
        float n1 = norm1[pix];
        float bestc = -2.f;
        int   bi = 0;
        for (int it = 0; it < 25; ++it) {
            int m = it * 64 + l;
            float g = col[(size_t)m * N];
            unsigned long long mask = __ballot(g >= gth);
            while (mask) {
                int s = __ffsll(mask) - 1;
                mask &= mask - 1;
                int mc = it * 64 + s;
                const float* p2 = fs2 + (size_t)b * D * N + mc;
                float acc = 0.f;
                #pragma unroll
                for (int d8 = 0; d8 < 8; ++d8) {
                    int d = d8 * 64 + l;
                    acc = fmaf(p1[(size_t)d * N], p2[(size_t)d * N], acc);
                }
                #pragma unroll
                for (int off = 1; off < 64; off <<= 1)
                    acc += __shfl_xor(acc, off, 64);
                float cc = acc / (n1 * norm2[b * N + mc] + EPS_K);
                if (cc > bestc) { bestc = cc; bi = mc; }
            }
        }
        if (l == 0) bestm[pix] = bi;
    }
}

// ---------------- Kernel E: flow + certainty ----------------
__global__ __launch_bounds__(256)
void flow_kernel(float* __restrict__ out, const int* __restrict__ bestm) {
    int id = blockIdx.x * 256 + threadIdx.x;
    if (id >= B * N) return;
    int b = id / N, n = id % N;
    int bm = bestm[id];
    int i = bm / NRES, j = bm % NRES;
    const float step = 1.95f / 39.f;
    float gx = fmaf(step, (float)j, -0.975f);
    float gy = fmaf(step, (float)i, -0.975f);
    const size_t CERT_OFF = (size_t)B * N * N;
    const size_t FLOW_OFF = CERT_OFF + (size_t)B * N;
    out[CERT_OFF + id] = 0.f;
    out[FLOW_OFF + (size_t)(b * 2) * N + n]     = gx;
    out[FLOW_OFF + (size_t)(b * 2 + 1) * N + n] = gy;
}

extern "C" void kernel_launch(void* const* d_in, const int* in_sizes, int n_in,
                              void* d_out, int out_size, void* d_ws, size_t ws_size,
                              hipStream_t stream) {
    const float* fs1 = (const float*)d_in[0];
    const float* fs2 = (const float*)d_in[1];
    float* out = (float*)d_out;

    const size_t SPLIT = (size_t)B * NP * D;                 // elems per split array
    const size_t SMALL = 5 * (size_t)B * N * 4 + 16 * (size_t)B * N * 4 + 64;
    const size_t NEED_MID  = 2 * SPLIT * sizeof(short)       // Yh,Xh (fp16 transposed)
                           + 2 * SPLIT * sizeof(float)       // Yf,Xf (fp32 transposed)
                           + SMALL;
    const size_t NEED_FULL = NEED_MID + (size_t)B * N * N * sizeof(unsigned short);  // + Kh

    if (ws_size >= NEED_MID) {
        bool full = (ws_size >= NEED_FULL);
        short* Yh = (short*)d_ws;
        short* Xh = Yh + SPLIT;
        float* Yf = (float*)(Xh + SPLIT);
        float* Xf = Yf + SPLIT;
        unsigned short* Kh = (unsigned short*)(Xf + SPLIT);  // only if full
        char* tail = (char*)(Kh + (full ? (size_t)B * N * N : 0));
        float* norm1 = (float*)tail;
        float* norm2 = norm1 + B * N;
        unsigned int* mx = (unsigned int*)(norm2 + B * N);
        int* bestm = (int*)(mx + B * N);
        unsigned int* candCount = (unsigned int*)(bestm + B * N);
        int* candM = (int*)(candCount + B * N);
        float* partial = out;    // scratch inside gm_cls region, overwritten later

        hipMemsetAsync(mx, 0, B * N * sizeof(unsigned int), stream);
        hipMemsetAsync(bestm, 0x7f, B * N * sizeof(int), stream);
        hipMemsetAsync(candCount, 0, B * N * sizeof(unsigned int), stream);

        split_transpose_kernel<<<dim3(26, 8, 16), 256, 0, stream>>>(
            fs1, fs2, Xh, Yh, Xf, Yf, partial);
        norms_reduce_kernel<<<dim3(100), 256, 0, stream>>>(partial, norm1, norm2);
        if (full) {
            gemm_fp16_kernel<true><<<dim3(1352), 256, 0, stream>>>(Yh, Xh, norm1, norm2,
                                                                   mx, out, Kh);
            fix_argmax_f16_kernel<<<dim3(7, 32, B), 256, 0, stream>>>(Kh, out, mx, bestm,
                                                                      candCount, candM);
        } else {
            gemm_fp16_kernel<false><<<dim3(1352), 256, 0, stream>>>(Yh, Xh, norm1, norm2,
                                                                    mx, out, nullptr);
            fix_argmax_kernel<<<dim3(7, 32, B), 256, 0, stream>>>(out, mx, bestm,
                                                                  candCount, candM);
        }
        refine_kernel<<<dim3(320), 256, 0, stream>>>(Xf, Yf, norm1, norm2,
                                                     candCount, candM, bestm);
        flow_kernel<<<dim3((B * N + 255) / 256), 256, 0, stream>>>(out, bestm);
    } else {
        float* norm1 = (float*)d_ws;
        float* norm2 = norm1 + B * N;
        unsigned int* mx = (unsigned int*)(norm2 + B * N);
        int* bestm = (int*)(mx + B * N);
        unsigned int* candCount = (unsigned int*)(bestm + B * N);
        int* candM = (int*)(candCount + B * N);

        hipMemsetAsync(mx, 0, B * N * sizeof(unsigned int), stream);
        hipMemsetAsync(bestm, 0x7f, B * N * sizeof(int), stream);
        hipMemsetAsync(candCount, 0, B * N * sizeof(unsigned int), stream);

        norms_kernel<<<dim3(2 * B * 25), 256, 0, stream>>>(fs1, fs2, norm1, norm2);
        gemm_exp_kernel<<<dim3(13, 13, B), 256, 0, stream>>>(fs1, fs2, norm1, norm2, mx, out);
        fix_argmax_kernel<<<dim3(7, 32, B), 256, 0, stream>>>(out, mx, bestm,
                                                              candCount, candM);
        refine_fb_kernel<<<dim3(320), 256, 0, stream>>>(fs1, fs2, norm1, norm2,
                                                        mx, candCount, bestm, out);
        flow_kernel<<<dim3((B * N + 255) / 256), 256, 0, stream>>>(out, bestm);
    }
}

// Round 15
// 102.686 us; speedup vs baseline: 4.2440x; 4.2440x over previous
//
#include <hip/hip_runtime.h>
#include <math.h>

#define B 8
#define D 512
#define N 1600
#define NP 1664      // padded N (13 * 128) -- physical row count of split arrays
#define NRES 40

static constexpr float EPS_K   = 1e-6f;
static constexpr float INV_T   = 10.0f;  // 1/T
static constexpr float SCALE_K = 10.0f;
static constexpr float BAND    = 0.99f;  // candidate band (rel. to max K); c-window 1.0e-3
static constexpr float L2E10   = 14.4269504089f; // 10*log2(e)

using f32x4 = __attribute__((ext_vector_type(4))) float;
using h8    = __attribute__((ext_vector_type(8))) _Float16;
using u16x4 = __attribute__((ext_vector_type(4))) unsigned short;

// ---------------- helpers ----------------
__device__ __forceinline__ void gload16(const void* g, void* l) {
    __builtin_amdgcn_global_load_lds(
        (const __attribute__((address_space(1))) void*)g,
        (__attribute__((address_space(3))) void*)l, 16, 0, 0);
}

// ---------------- Kernel A: fp32 -> fp16/fp32 transposed + norm partials + flag init ----------------
__global__ __launch_bounds__(256)
void split_transpose_kernel(const float* __restrict__ f1, const float* __restrict__ f2,
                            short* __restrict__ Xh, short* __restrict__ Yh,
                            float* __restrict__ Xf, float* __restrict__ Yf,
                            float* __restrict__ partial,
                            unsigned int* __restrict__ mx, int* __restrict__ bestm,
                            unsigned int* __restrict__ candCount) {
    int bx = blockIdx.x;           // n-tile of 64 (0..25, covers NP)
    int by = blockIdx.y;           // d-tile of 64 (0..7)
    int bz = blockIdx.z;
    int b = bz & 7, which = bz >> 3;
    const float* src = which ? f2 : f1;
    short* oh = which ? Yh : Xh;
    float* of = which ? Yf : Xf;

    // fold flag-array init into the by==0 wavefront of blocks (runs before any reader)
    if (by == 0) {
        int id = (bx * 16 + bz) * 256 + threadIdx.x;   // 0 .. 106495 >= B*N
        if (id < B * N) {
            mx[id] = 0u;
            bestm[id] = 0x7f7f7f7f;
            candCount[id] = 0u;
        }
    }

    __shared__ float Ts[64][65];
    __shared__ float red[64][17];
    int t = threadIdx.x;
    int n0 = bx * 64, d0 = by * 64;
    bool valid = (n0 < N);         // bx==25 is the zero-pad tile
    int c4 = (t & 15) * 4, g16 = t >> 4;

    #pragma unroll
    for (int p = 0; p < 4; ++p) {
        int dl = g16 + p * 16;
        float4 v = make_float4(0.f, 0.f, 0.f, 0.f);
        if (valid) v = *(const float4*)&src[((size_t)b * D + d0 + dl) * N + n0 + c4];
        Ts[dl][c4 + 0] = v.x; Ts[dl][c4 + 1] = v.y;
        Ts[dl][c4 + 2] = v.z; Ts[dl][c4 + 3] = v.w;
    }
    __syncthreads();
    #pragma unroll
    for (int p = 0; p < 4; ++p) {
        int nl = g16 + p * 16;
        float vv[4];
        unsigned int hw[2];
        float ssp = 0.f;
        #pragma unroll
        for (int q = 0; q < 2; ++q) {
            unsigned int wv = 0;
            #pragma unroll
            for (int i = 0; i < 2; ++i) {
                float v = Ts[c4 + q * 2 + i][nl];
                vv[q * 2 + i] = v;
                ssp = fmaf(v, v, ssp);
                _Float16 h = (_Float16)v;            // round-to-nearest-even
                unsigned short hb = __builtin_bit_cast(unsigned short, h);
                wv |= ((unsigned int)hb) << (16 * i);
            }
            hw[q] = wv;
        }
        red[nl][c4 >> 2] = ssp;
        size_t o = ((size_t)b * NP + n0 + nl) * D + d0 + c4;
        *(uint2*)&oh[o] = make_uint2(hw[0], hw[1]);
        *(float4*)&of[o] = make_float4(vv[0], vv[1], vv[2], vv[3]);
    }
    __syncthreads();
    if (t < 64) {
        float s = 0.f;
        #pragma unroll
        for (int g = 0; g < 16; ++g) s += red[t][g];
        partial[(((size_t)which * 8 + b) * 8 + by) * NP + n0 + t] = s;
    }
}

// ---------------- Kernel A2: reduce norm partials ----------------
__global__ __launch_bounds__(256)
void norms_reduce_kernel(const float* __restrict__ partial,
                         float* __restrict__ norm1, float* __restrict__ norm2) {
    int id = blockIdx.x * 256 + threadIdx.x;   // over 2*B*N
    if (id >= 2 * B * N) return;
    int which = id / (B * N);
    int r = id % (B * N);
    int b = r / N, n = r % N;
    float s = 0.f;
    #pragma unroll
    for (int dt = 0; dt < 8; ++dt)
        s += partial[(((size_t)which * 8 + b) * 8 + dt) * NP + n];
    (which ? norm2 : norm1)[b * N + n] = sqrtf(s);
}

// ---------------- Kernel B (fallback path): column norms ----------------
__global__ __launch_bounds__(256)
void norms_kernel(const float* __restrict__ fs1, const float* __restrict__ fs2,
                  float* __restrict__ norm1, float* __restrict__ norm2) {
    int bid   = blockIdx.x;
    int ntile = bid % 25;
    int b     = (bid / 25) % B;
    int which = bid / (25 * B);
    const float* src = which ? fs2 : fs1;
    float*       dst = which ? norm2 : norm1;

    int t = threadIdx.x, nl = t & 63, doff = t >> 6;
    int n = ntile * 64 + nl;
    const float* base = src + (size_t)b * D * N + n;
    float acc = 0.f;
    for (int d = doff; d < D; d += 4) {
        float v = base[(size_t)d * N];
        acc = fmaf(v, v, acc);
    }
    __shared__ float red[4][64];
    red[doff][nl] = acc;
    __syncthreads();
    if (t < 64) {
        float s = red[0][t] + red[1][t] + red[2][t] + red[3][t];
        dst[b * N + ntile * 64 + t] = sqrtf(s);
    }
}

// ---------------- Kernel C: fp16 MFMA GEMM, 128x128, dbuf counted vmcnt, 4 blocks/CU ----------------
// NOTE: do NOT raise the min-waves bound: 60 VGPR + 64 AGPR (unified) needs the 128-reg budget of
// 4 waves/SIMD; (256,5)/(256,8) cap regs at 102/64 and spill the accumulator (R11/R14 regressions).
__device__ __forceinline__ h8 ldfragh(const short* tile, int row, int l) {
    int s = ((l >> 4) ^ (row >> 1)) & 3;   // bank-spread XOR swizzle
    return *(const h8*)(tile + row * 32 + s * 8);
}

template<bool USE_KH>
__global__ __launch_bounds__(256, 4)
void gemm_fp16_kernel(const short* __restrict__ Yh, const short* __restrict__ Xh,
                      const float* __restrict__ norm1, const float* __restrict__ norm2,
                      unsigned int* __restrict__ mx, float* __restrict__ out,
                      unsigned short* __restrict__ Kh) {
    // 2 buffers x [A 8KB | B 8KB] = 32KB -> 4 blocks/CU
    __shared__ short lds[2][8192];

    int lin = blockIdx.x;          // 1352 = 8 XCD * 169
    int b    = lin & 7;            // one batch per XCD (T1)
    int rem  = lin >> 3;           // 0..168
    int mblk = rem % 13;           // m fastest -> X-panel L2 reuse
    int nblk = rem / 13;           // 0..12
    int m0 = mblk * 128, n0 = nblk * 128;

    int t = threadIdx.x, l = t & 63, w = t >> 6;
    int mwoff = (w & 1) * 64;      // wave tile 64x64
    int nwoff = (w >> 1) * 64;
    size_t bNP = (size_t)b * NP;
    int l15 = l & 15;

    // --- staging: 16 units of 1KB (A rowgroups 0-7, B rowgroups 0-7); 4 gload16/thread ---
    const short* gp[4];
    int lo[4];
    #pragma unroll
    for (int j = 0; j < 4; ++j) {
        int q = w * 4 + j;
        int tile = q >> 3, rg = q & 7;
        int row  = rg * 16 + (l >> 2);
        int slotg = (l & 3) ^ ((row >> 1) & 3);   // pre-swizzled global source
        const short* base = tile ? Xh : Yh;
        int rows0 = tile ? n0 : m0;
        gp[j] = base + (bNP + rows0 + row) * (size_t)D + slotg * 8;
        lo[j] = tile * 4096 + rg * 512;           // wave-uniform LDS base (shorts)
    }

    #define ST(nb)                                             \
    {   _Pragma("unroll")                                      \
        for (int j = 0; j < 4; ++j) {                          \
            gload16(gp[j], &lds[nb][lo[j]]);                   \
            gp[j] += 32;                                       \
        }                                                      \
    }

    f32x4 acc[4][4];
    #pragma unroll
    for (int i = 0; i < 4; i++)
        #pragma unroll
        for (int j = 0; j < 4; j++) acc[i][j] = (f32x4)0.f;

    ST(0);   // prologue: K-tile 0 into buffer 0

    for (int tt = 0; tt < 16; ++tt) {
        int cur = tt & 1;
        if (tt < 15) {
            ST(cur ^ 1);                                       // prefetch next K-tile
            asm volatile("s_waitcnt vmcnt(4)" ::: "memory");   // cur tile landed; 4 in flight
        } else {
            asm volatile("s_waitcnt vmcnt(0)" ::: "memory");
        }
        __builtin_amdgcn_s_barrier();
        asm volatile("" ::: "memory");

        const short* Ah = &lds[cur][0];
        const short* Bh = &lds[cur][4096];

        h8 bh[4];
        #pragma unroll
        for (int nj = 0; nj < 4; ++nj)
            bh[nj] = ldfragh(Bh, nwoff + nj * 16 + l15, l);
        __builtin_amdgcn_s_setprio(1);
        #pragma unroll
        for (int mi = 0; mi < 4; ++mi) {
            h8 ah = ldfragh(Ah, mwoff + mi * 16 + l15, l);
            #pragma unroll
            for (int nj = 0; nj < 4; ++nj)
                acc[mi][nj] = __builtin_amdgcn_mfma_f32_16x16x32_f16(ah, bh[nj], acc[mi][nj], 0, 0, 0);
        }
        __builtin_amdgcn_s_setprio(0);
        asm volatile("s_waitcnt lgkmcnt(0)" ::: "memory");     // LDS reads retired before overwrite
        __builtin_amdgcn_s_barrier();
    }
    #undef ST

    // epilogue: c = acc*rn1*rn2; K = exp2((c-1)*10*log2e); store K (fp16 to Kh or fp32 to out); per-n max
    int hi4 = l >> 4;
    float rn1v[4];
    int   ng[4];
    #pragma unroll
    for (int nj = 0; nj < 4; ++nj) {
        ng[nj]  = n0 + nwoff + nj * 16 + l15;
        float n1 = (ng[nj] < N) ? norm1[b * N + ng[nj]] : 1.f;
        rn1v[nj] = __builtin_amdgcn_rcpf(n1);
    }
    float pmax[4] = {0.f, 0.f, 0.f, 0.f};
    size_t obase = (size_t)b * N * N;

    #pragma unroll
    for (int mi = 0; mi < 4; ++mi) {
        #pragma unroll
        for (int r = 0; r < 4; ++r) {
            int mg = m0 + mwoff + mi * 16 + hi4 * 4 + r;
            bool mok = (mg < N);
            float rn2 = mok ? __builtin_amdgcn_rcpf(norm2[b * N + mg]) : 1.f;
            #pragma unroll
            for (int nj = 0; nj < 4; ++nj) {
                float c = acc[mi][nj][r] * rn2 * rn1v[nj];
                float k = exp2f((c - 1.f) * L2E10);
                if (!mok) k = 0.f;
                if constexpr (USE_KH) {
                    _Float16 h = (_Float16)k;                 // stored value
                    float kr = (float)h;
                    pmax[nj] = fmaxf(pmax[nj], kr);           // max over STORED values
                    if (mok && ng[nj] < N)
                        Kh[obase + (size_t)mg * N + ng[nj]] = __builtin_bit_cast(unsigned short, h);
                } else {
                    pmax[nj] = fmaxf(pmax[nj], k);
                    if (mok && ng[nj] < N)
                        out[obase + (size_t)mg * N + ng[nj]] = k;
                }
            }
        }
    }
    #pragma unroll
    for (int nj = 0; nj < 4; ++nj) {
        float v = pmax[nj];
        v = fmaxf(v, __shfl_xor(v, 16, 64));
        v = fmaxf(v, __shfl_xor(v, 32, 64));
        if (hi4 == 0 && ng[nj] < N)
            atomicMax(&mx[b * N + ng[nj]], __float_as_uint(v));
    }
}

// ---------------- fp32 fallback GEMM (used if ws too small) ----------------
#define BK 16
#define BT 128
__global__ __launch_bounds__(256)
void gemm_exp_kernel(const float* __restrict__ fs1, const float* __restrict__ fs2,
                     const float* __restrict__ norm1, const float* __restrict__ norm2,
                     unsigned int* __restrict__ mx, float* __restrict__ out) {
    int m0 = blockIdx.x * BT, n0 = blockIdx.y * BT, b = blockIdx.z;
    int t = threadIdx.x, tx = t & 15, ty = t >> 4;
    __shared__ float Xs[BK][BT];
    __shared__ float Ys[BK][BT];
    __shared__ float red[BT][17];
    const float* Xb = fs1 + (size_t)b * D * N;
    const float* Yb = fs2 + (size_t)b * D * N;
    float acc[8][8];
    #pragma unroll
    for (int i = 0; i < 8; i++)
        #pragma unroll
        for (int j = 0; j < 8; j++) acc[i][j] = 0.f;
    int r0 = t >> 5, c4 = (t & 31) * 4;
    bool xok = (n0 + c4) < N, yok = (m0 + c4) < N;
    for (int kk = 0; kk < D; kk += BK) {
        #pragma unroll
        for (int rr = 0; rr < 2; rr++) {
            int r = r0 + rr * 8, d = kk + r;
            float4 xv = make_float4(0, 0, 0, 0), yv = make_float4(0, 0, 0, 0);
            if (xok) xv = *(const float4*)&Xb[(size_t)d * N + n0 + c4];
            if (yok) yv = *(const float4*)&Yb[(size_t)d * N + m0 + c4];
            *(float4*)&Xs[r][c4] = xv;
            *(float4*)&Ys[r][c4] = yv;
        }
        __syncthreads();
        #pragma unroll
        for (int d = 0; d < BK; d++) {
            float4 a0 = *(const float4*)&Xs[d][ty * 4];
            float4 a1 = *(const float4*)&Xs[d][64 + ty * 4];
            float4 b0 = *(const float4*)&Ys[d][tx * 4];
            float4 b1 = *(const float4*)&Ys[d][64 + tx * 4];
            float av[8] = {a0.x, a0.y, a0.z, a0.w, a1.x, a1.y, a1.z, a1.w};
            float bv[8] = {b0.x, b0.y, b0.z, b0.w, b1.x, b1.y, b1.z, b1.w};
            #pragma unroll
            for (int i = 0; i < 8; i++)
                #pragma unroll
                for (int j = 0; j < 8; j++)
                    acc[i][j] = fmaf(av[i], bv[j], acc[i][j]);
        }
        __syncthreads();
    }
    int ng[8], mg[8];
    float n1v[8], n2v[8];
    #pragma unroll
    for (int q = 0; q < 8; q++) {
        ng[q] = n0 + ((q < 4) ? (ty * 4 + q) : (64 + ty * 4 + q - 4));
        mg[q] = m0 + ((q < 4) ? (tx * 4 + q) : (64 + tx * 4 + q - 4));
        n1v[q] = (ng[q] < N) ? norm1[b * N + ng[q]] : 1.f;
        n2v[q] = (mg[q] < N) ? norm2[b * N + mg[q]] : 1.f;
    }
    float pmax[8];
    #pragma unroll
    for (int i = 0; i < 8; i++) pmax[i] = 0.f;
    size_t obase = (size_t)b * N * N;
    #pragma unroll
    for (int j = 0; j < 8; j++) {
        float kcol[8];
        #pragma unroll
        for (int i = 0; i < 8; i++) {
            float c = acc[i][j] / (n1v[i] * n2v[j] + EPS_K);
            float k = expf((c - 1.f) * INV_T);
            if (mg[j] >= N) k = 0.f;
            kcol[i] = k;
            pmax[i] = fmaxf(pmax[i], k);
        }
        if (mg[j] < N) {
            size_t rowb = obase + (size_t)mg[j] * N;
            float4 v0 = {kcol[0], kcol[1], kcol[2], kcol[3]};
            *(float4*)&out[rowb + ng[0]] = v0;
            if (ng[4] < N) {
                float4 v1 = {kcol[4], kcol[5], kcol[6], kcol[7]};
                *(float4*)&out[rowb + ng[4]] = v1;
            }
        }
    }
    #pragma unroll
    for (int q = 0; q < 8; q++) {
        int nloc = (q < 4) ? (ty * 4 + q) : (64 + ty * 4 + q - 4);
        red[nloc][tx] = pmax[q];
    }
    __syncthreads();
    if (t < BT) {
        float mval = red[t][0];
        #pragma unroll
        for (int x = 1; x < 16; x++) mval = fmaxf(mval, red[t][x]);
        int n = n0 + t;
        if (n < N) atomicMax(&mx[b * N + n], __float_as_uint(mval));
    }
}

// ---------------- Kernel D (fp16-K): read Kh, write gm_cls, band-candidate list (XCD-aligned) ----------------
__global__ __launch_bounds__(256)
void fix_argmax_f16_kernel(const unsigned short* __restrict__ Kh, float* __restrict__ out,
                           const unsigned int* __restrict__ mx, int* __restrict__ bestm,
                           unsigned int* __restrict__ candCount, int* __restrict__ candM) {
    int lin = blockIdx.x;     // 1792 = 8 XCD * 224; b on the XCD that wrote batch b's Kh
    int b   = lin & 7;
    int rest = lin >> 3;      // 0..223
    int nt  = rest % 7;       // n chunk of 256
    int mq  = rest / 7;       // 0..31 (m chunks of 50)
    int t   = threadIdx.x;
    int n0 = nt * 256 + (t & 63) * 4;
    int moff = t >> 6;
    if (n0 >= N) return;      // N%4==0 -> full 4-col group valid or fully out

    float4 mxv = *(const float4*)&((const float*)mx)[b * N + n0];
    float4 th  = make_float4(mxv.x * BAND, mxv.y * BAND, mxv.z * BAND, mxv.w * BAND);
    size_t base = (size_t)b * N * N + n0;
    int mend = mq * 50 + 50;
    for (int m = mq * 50 + moff; m < mend; m += 4) {
        size_t idx = base + (size_t)m * N;
        u16x4 kv = *(const u16x4*)&Kh[idx];
        float k0 = (float)__builtin_bit_cast(_Float16, (unsigned short)kv[0]);
        float k1 = (float)__builtin_bit_cast(_Float16, (unsigned short)kv[1]);
        float k2 = (float)__builtin_bit_cast(_Float16, (unsigned short)kv[2]);
        float k3 = (float)__builtin_bit_cast(_Float16, (unsigned short)kv[3]);
        float4 o;
        o.x = (k0 - mxv.x) * SCALE_K;
        o.y = (k1 - mxv.y) * SCALE_K;
        o.z = (k2 - mxv.z) * SCALE_K;
        o.w = (k3 - mxv.w) * SCALE_K;
        *(float4*)&out[idx] = o;
        #pragma unroll
        for (int j = 0; j < 4; ++j) {
            float vv = (j == 0) ? k0 : (j == 1) ? k1 : (j == 2) ? k2 : k3;
            float tt = (j == 0) ? th.x : (j == 1) ? th.y : (j == 2) ? th.z : th.w;
            if (vv >= tt) {
                int pix = b * N + n0 + j;
                unsigned int slot = atomicAdd(&candCount[pix], 1u);  // scattered, ~1/pixel
                if (slot < 15) candM[pix * 16 + slot] = m;
                atomicMin(&bestm[pix], m);
            }
        }
    }
}

// ---------------- Kernel D (fp32-K in-place, mid fallback) ----------------
__global__ __launch_bounds__(256)
void fix_argmax_kernel(float* __restrict__ out, const unsigned int* __restrict__ mx,
                       int* __restrict__ bestm, unsigned int* __restrict__ candCount,
                       int* __restrict__ candM) {
    int nt = blockIdx.x;
    int mq = blockIdx.y;
    int b  = blockIdx.z;
    int t  = threadIdx.x;
    int n0 = nt * 256 + (t & 63) * 4;
    int moff = t >> 6;
    if (n0 >= N) return;

    float4 mxv = *(const float4*)&((const float*)mx)[b * N + n0];
    float4 th  = make_float4(mxv.x * BAND, mxv.y * BAND, mxv.z * BAND, mxv.w * BAND);
    size_t base = (size_t)b * N * N + n0;
    int mend = mq * 50 + 50;
    for (int m = mq * 50 + moff; m < mend; m += 4) {
        size_t idx = base + (size_t)m * N;
        float4 v = *(float4*)&out[idx];
        float4 o;
        o.x = (v.x - mxv.x) * SCALE_K;
        o.y = (v.y - mxv.y) * SCALE_K;
        o.z = (v.z - mxv.z) * SCALE_K;
        o.w = (v.w - mxv.w) * SCALE_K;
        *(float4*)&out[idx] = o;
        #pragma unroll
        for (int j = 0; j < 4; ++j) {
            float vv = (j == 0) ? v.x : (j == 1) ? v.y : (j == 2) ? v.z : v.w;
            float tt = (j == 0) ? th.x : (j == 1) ? th.y : (j == 2) ? th.z : th.w;
            if (vv >= tt) {
                int pix = b * N + n0 + j;
                unsigned int slot = atomicAdd(&candCount[pix], 1u);
                if (slot < 15) candM[pix * 16 + slot] = m;
                atomicMin(&bestm[pix], m);
            }
        }
    }
}

// ---------------- Kernel D2: exact refinement via candidate list (coalesced fp32T reads) ----------------
__global__ __launch_bounds__(256)
void refine_kernel(const float* __restrict__ Xf, const float* __restrict__ Yf,
                   const float* __restrict__ norm1, const float* __restrict__ norm2,
                   const unsigned int* __restrict__ candCount, const int* __restrict__ candM,
                   int* __restrict__ bestm) {
    int nwaves = (gridDim.x * 256) >> 6;
    int wv = (blockIdx.x * 256 + threadIdx.x) >> 6;
    int l  = threadIdx.x & 63;
    for (int pix = wv; pix < B * N; pix += nwaves) {
        unsigned int cnt = candCount[pix];
        if (cnt < 2) continue;                        // unique band member == exact argmax
        int b = pix / N, n = pix % N;
        const float* p1 = Xf + ((size_t)b * NP + n) * D;
        float n1 = norm1[pix];
        float bestc = -2.f;
        int   bi = N;
        int ncand = (cnt <= 15) ? (int)cnt : N;       // overflow (>15): exact scan of all m
        for (int e = 0; e < ncand; ++e) {
            int m = (cnt <= 15) ? candM[pix * 16 + e] : e;
            const float* p2 = Yf + ((size_t)b * NP + m) * D;
            float acc = 0.f;
            #pragma unroll
            for (int q = 0; q < 2; ++q) {             // lane l: d = l*8 .. l*8+7 (coalesced)
                float4 a = *(const float4*)&p1[l * 8 + q * 4];
                float4 c = *(const float4*)&p2[l * 8 + q * 4];
                acc = fmaf(a.x, c.x, acc);
                acc = fmaf(a.y, c.y, acc);
                acc = fmaf(a.z, c.z, acc);
                acc = fmaf(a.w, c.w, acc);
            }
            #pragma unroll
            for (int off = 1; off < 64; off <<= 1)
                acc += __shfl_xor(acc, off, 64);
            float cc = acc / (n1 * norm2[b * N + m] + EPS_K);
            if (cc > bestc || (cc == bestc && m < bi)) { bestc = cc; bi = m; }  // order-independent
        }
        if (l == 0) bestm[pix] = bi;                  // one wave owns this pixel
    }
}

// ---------------- Kernel D2-fb: fallback refinement (strided originals) ----------------
__global__ __launch_bounds__(256)
void refine_fb_kernel(const float* __restrict__ fs1, const float* __restrict__ fs2,
                      const float* __restrict__ norm1, const float* __restrict__ norm2,
                      const unsigned int* __restrict__ mx, const unsigned int* __restrict__ candCount,
                      int* __restrict__ bestm, const float* __restrict__ out) {
    int nwaves = (gridDim.x * 256) >> 6;
    int wv = (blockIdx.x * 256 + threadIdx.x) >> 6;
    int l  = threadIdx.x & 63;
    for (int pix = wv; pix < B * N; pix += nwaves) {
        if (candCount[pix] < 2) continue;
        int b = pix / N, n = pix % N;
        float mxv = __uint_as_float(mx[pix]);
        float gth = -(1.f - BAND) * SCALE_K * mxv;
        const float* col = out + (size_t)b * N * N + n;
        const float* p1  = fs1 + (size_t)b * D * N + n;
        float n1 = norm1[pix];
        float bestc = -2.f;
        int   bi = 0;
        for (int it = 0; it < 25; ++it) {
            int m = it * 64 + l;
            float g = col[(size_t)m * N];
            unsigned long long mask = __ballot(g >= gth);
            while (mask) {
                int s = __ffsll(mask) - 1;
                mask &= mask - 1;
                int mc = it * 64 + s;
                const float* p2 = fs2 + (size_t)b * D * N + mc;
                float acc = 0.f;
                #pragma unroll
                for (int d8 = 0; d8 < 8; ++d8) {
                    int d = d8 * 64 + l;
                    acc = fmaf(p1[(size_t)d * N], p2[(size_t)d * N], acc);
                }
                #pragma unroll
                for (int off = 1; off < 64; off <<= 1)
                    acc += __shfl_xor(acc, off, 64);
                float cc = acc / (n1 * norm2[b * N + mc] + EPS_K);
                if (cc > bestc) { bestc = cc; bi = mc; }
            }
        }
        if (l == 0) bestm[pix] = bi;
    }
}

// ---------------- Kernel E: flow + certainty ----------------
__global__ __launch_bounds__(256)
void flow_kernel(float* __restrict__ out, const int* __restrict__ bestm) {
    int id = blockIdx.x * 256 + threadIdx.x;
    if (id >= B * N) return;
    int b = id / N, n = id % N;
    int bm = bestm[id];
    int i = bm / NRES, j = bm % NRES;
    const float step = 1.95f / 39.f;
    float gx = fmaf(step, (float)j, -0.975f);
    float gy = fmaf(step, (float)i, -0.975f);
    const size_t CERT_OFF = (size_t)B * N * N;
    const size_t FLOW_OFF = CERT_OFF + (size_t)B * N;
    out[CERT_OFF + id] = 0.f;
    out[FLOW_OFF + (size_t)(b * 2) * N + n]     = gx;
    out[FLOW_OFF + (size_t)(b * 2 + 1) * N + n] = gy;
}

extern "C" void kernel_launch(void* const* d_in, const int* in_sizes, int n_in,
                              void* d_out, int out_size, void* d_ws, size_t ws_size,
                              hipStream_t stream) {
    const float* fs1 = (const float*)d_in[0];
    const float* fs2 = (const float*)d_in[1];
    float* out = (float*)d_out;

    const size_t SPLIT = (size_t)B * NP * D;                 // elems per split array
    const size_t SMALL = 5 * (size_t)B * N * 4 + 16 * (size_t)B * N * 4 + 64;
    const size_t NEED_MID  = 2 * SPLIT * sizeof(short)       // Yh,Xh (fp16 transposed)
                           + 2 * SPLIT * sizeof(float)       // Yf,Xf (fp32 transposed)
                           + SMALL;
    const size_t NEED_FULL = NEED_MID + (size_t)B * N * N * sizeof(unsigned short);  // + Kh

    if (ws_size >= NEED_MID) {
        bool full = (ws_size >= NEED_FULL);
        short* Yh = (short*)d_ws;
        short* Xh = Yh + SPLIT;
        float* Yf = (float*)(Xh + SPLIT);
        float* Xf = Yf + SPLIT;
        unsigned short* Kh = (unsigned short*)(Xf + SPLIT);  // only if full
        char* tail = (char*)(Kh + (full ? (size_t)B * N * N : 0));
        float* norm1 = (float*)tail;
        float* norm2 = norm1 + B * N;
        unsigned int* mx = (unsigned int*)(norm2 + B * N);
        int* bestm = (int*)(mx + B * N);
        unsigned int* candCount = (unsigned int*)(bestm + B * N);
        int* candM = (int*)(candCount + B * N);
        float* partial = out;    // scratch inside gm_cls region, overwritten later

        split_transpose_kernel<<<dim3(26, 8, 16), 256, 0, stream>>>(
            fs1, fs2, Xh, Yh, Xf, Yf, partial, mx, bestm, candCount);
        norms_reduce_kernel<<<dim3(100), 256, 0, stream>>>(partial, norm1, norm2);
        if (full) {
            gemm_fp16_kernel<true><<<dim3(1352), 256, 0, stream>>>(Yh, Xh, norm1, norm2,
                                                                   mx, out, Kh);
            fix_argmax_f16_kernel<<<dim3(1792), 256, 0, stream>>>(Kh, out, mx, bestm,
                                                                  candCount, candM);
        } else {
            gemm_fp16_kernel<false><<<dim3(1352), 256, 0, stream>>>(Yh, Xh, norm1, norm2,
                                                                    mx, out, nullptr);
            fix_argmax_kernel<<<dim3(7, 32, B), 256, 0, stream>>>(out, mx, bestm,
                                                                  candCount, candM);
        }
        refine_kernel<<<dim3(320), 256, 0, stream>>>(Xf, Yf, norm1, norm2,
                                                     candCount, candM, bestm);
        flow_kernel<<<dim3((B * N + 255) / 256), 256, 0, stream>>>(out, bestm);
    } else {
        float* norm1 = (float*)d_ws;
        float* norm2 = norm1 + B * N;
        unsigned int* mx = (unsigned int*)(norm2 + B * N);
        int* bestm = (int*)(mx + B * N);
        unsigned int* candCount = (unsigned int*)(bestm + B * N);
        int* candM = (int*)(candCount + B * N);

        hipMemsetAsync(mx, 0, B * N * sizeof(unsigned int), stream);
        hipMemsetAsync(bestm, 0x7f, B * N * sizeof(int), stream);
        hipMemsetAsync(candCount, 0, B * N * sizeof(unsigned int), stream);

        norms_kernel<<<dim3(2 * B * 25), 256, 0, stream>>>(fs1, fs2, norm1, norm2);
        gemm_exp_kernel<<<dim3(13, 13, B), 256, 0, stream>>>(fs1, fs2, norm1, norm2, mx, out);
        fix_argmax_kernel<<<dim3(7, 32, B), 256, 0, stream>>>(out, mx, bestm,
                                                              candCount, candM);
        refine_fb_kernel<<<dim3(320), 256, 0, stream>>>(fs1, fs2, norm1, norm2,
                                                        mx, candCount, bestm, out);
        flow_kernel<<<dim3((B * N + 255) / 256), 256, 0, stream>>>(out, bestm);
    }
}